// Round 4
// baseline (1094.555 us; speedup 1.0000x reference)
//
#include <hip/hip_runtime.h>
#include <math.h>

#define WH 64
#define WIN 256
#define TT 4
#define ALPHA_C 0.1f
#define STATS_GRID 256
#define KC 32
#define ENC_T 128
#define ENC_BN 128
#define XT_STRIDE 132           // 128 + 4 floats: keeps float4 16B alignment, 2-way banks
#define BINS 16384              // bins over [-8, 8)
#define BIN_SCALE 1024.0f       // BINS / 16
#define HG 256                  // histogram grid (partial hists)
#define SB 128                  // scan blocks
#define ST 256                  // scan threads/block
#define BP 4                    // build passes (dst-range partition; 1.6MB L2 window)

typedef unsigned short ushortT;

__device__ __forceinline__ unsigned pack_bf16(float a, float b) {
  unsigned ua = __float_as_uint(a), ub = __float_as_uint(b);
  ua = (ua + 0x7FFFu + ((ua >> 16) & 1u)) >> 16;          // RNE
  ub = ((ub + 0x7FFFu + ((ub >> 16) & 1u)) >> 16) << 16;
  return (ua & 0xFFFFu) | ub;
}
__device__ __forceinline__ float bf_lo(unsigned p) { return __uint_as_float(p << 16); }
__device__ __forceinline__ float bf_hi(unsigned p) { return __uint_as_float(p & 0xFFFF0000u); }

// ---------- encode: H = l2norm_rows(X @ W + b) ----------
// outer-product tiling: 128 threads, 128 nodes/block, 8x8 acc per thread.
__global__ __launch_bounds__(128, 4) void k_encode(const float* __restrict__ X,
                                                   const float* __restrict__ W,
                                                   const float* __restrict__ bias,
                                                   float* __restrict__ H, int N) {
  __shared__ __align__(16) float XsT[KC * XT_STRIDE];  // 32*132*4 = 16.9 KB
  __shared__ __align__(16) float Ws[KC * WH];          // 8 KB
  int tid = threadIdx.x;
  int ng = tid >> 3, cg = tid & 7;   // ng: 16 node-groups of 8; cg: 8 col-groups of 8
  int nodeBase = blockIdx.x * ENC_BN;
  float acc[8][8] = {};
  for (int k0 = 0; k0 < WIN; k0 += KC) {
    __syncthreads();
    const float4* Wg4 = (const float4*)(W + (size_t)k0 * WH);
    float4* Ws4 = (float4*)Ws;
#pragma unroll
    for (int j = 0; j < 4; ++j) Ws4[tid + j * 128] = Wg4[tid + j * 128];
    float4 xv[8];
#pragma unroll
    for (int i = 0; i < 8; ++i) {
      int idx = tid + i * 128;
      int ln = idx >> 3, f4 = idx & 7;
      int node = nodeBase + ln;
      if (node < N)
        xv[i] = *(const float4*)(X + (size_t)node * WIN + k0 + f4 * 4);
      else
        xv[i] = make_float4(0.f, 0.f, 0.f, 0.f);
    }
#pragma unroll
    for (int i = 0; i < 8; ++i) {
      int idx = tid + i * 128;
      int ln = idx >> 3, f4 = idx & 7;
      float* p = &XsT[(f4 * 4) * XT_STRIDE + ln];
      p[0] = xv[i].x;
      p[XT_STRIDE] = xv[i].y;
      p[2 * XT_STRIDE] = xv[i].z;
      p[3 * XT_STRIDE] = xv[i].w;
    }
    __syncthreads();
#pragma unroll 4
    for (int k = 0; k < KC; ++k) {
      float4 a0 = *(const float4*)&XsT[k * XT_STRIDE + ng * 8];
      float4 a1 = *(const float4*)&XsT[k * XT_STRIDE + ng * 8 + 4];
      float4 b0 = *(const float4*)&Ws[k * WH + cg * 8];
      float4 b1 = *(const float4*)&Ws[k * WH + cg * 8 + 4];
      float av[8] = {a0.x, a0.y, a0.z, a0.w, a1.x, a1.y, a1.z, a1.w};
      float bb[8] = {b0.x, b0.y, b0.z, b0.w, b1.x, b1.y, b1.z, b1.w};
#pragma unroll
      for (int i = 0; i < 8; ++i)
#pragma unroll
        for (int j = 0; j < 8; ++j) acc[i][j] += av[i] * bb[j];
    }
  }
  float4 bb0 = *(const float4*)(bias + cg * 8);
  float4 bb1 = *(const float4*)(bias + cg * 8 + 4);
  float bv[8] = {bb0.x, bb0.y, bb0.z, bb0.w, bb1.x, bb1.y, bb1.z, bb1.w};
#pragma unroll
  for (int i = 0; i < 8; ++i) {
    float h[8];
    float s = 0.f;
#pragma unroll
    for (int j = 0; j < 8; ++j) {
      h[j] = acc[i][j] + bv[j];
      s += h[j] * h[j];
    }
    s += __shfl_xor(s, 1, 64);
    s += __shfl_xor(s, 2, 64);
    s += __shfl_xor(s, 4, 64);
    float r = 1.0f / fmaxf(sqrtf(s), 1e-12f);
    int node = nodeBase + ng * 8 + i;
    if (node < N) {
      float4 o0 = {h[0] * r, h[1] * r, h[2] * r, h[3] * r};
      float4 o1 = {h[4] * r, h[5] * r, h[6] * r, h[7] * r};
      *(float4*)(H + (size_t)node * WH + cg * 8) = o0;
      *(float4*)(H + (size_t)node * WH + cg * 8 + 4) = o1;
    }
  }
}

// ---------- per-type stats: fused sum + sumsq + counts ----------
__global__ __launch_bounds__(256) void k_stats(const float* __restrict__ H,
                                               const int* __restrict__ nt,
                                               float* __restrict__ psum,
                                               float* __restrict__ psq,
                                               float* __restrict__ pcnt, int NW) {
  __shared__ float ls[TT * WH], ls2[TT * WH];
  __shared__ float lc[TT];
  ls[threadIdx.x] = 0.0f;
  ls2[threadIdx.x] = 0.0f;
  if (threadIdx.x < TT) lc[threadIdx.x] = 0.0f;
  __syncthreads();
  for (int i = blockIdx.x * 256 + threadIdx.x; i < NW; i += STATS_GRID * 256) {
    int nn = i >> 6, d = i & 63;
    int t = nt[nn];
    float v = H[i];
    atomicAdd(&ls[t * WH + d], v);
    atomicAdd(&ls2[t * WH + d], v * v);
    if (d == 0) atomicAdd(&lc[t], 1.0f);
  }
  __syncthreads();
  psum[blockIdx.x * 256 + threadIdx.x] = ls[threadIdx.x];
  psq[blockIdx.x * 256 + threadIdx.x] = ls2[threadIdx.x];
  if (threadIdx.x < TT) pcnt[blockIdx.x * TT + threadIdx.x] = lc[threadIdx.x];
}

__global__ __launch_bounds__(256) void k_reduce_stats(const float* __restrict__ psum,
                                                      const float* __restrict__ psq,
                                                      const float* __restrict__ pcnt,
                                                      float* __restrict__ mean,
                                                      float* __restrict__ stdv,
                                                      float* __restrict__ counts) {
  __shared__ float c[TT];
  if (threadIdx.x < TT) {
    float s = 0.0f;
    for (int b = 0; b < STATS_GRID; ++b) s += pcnt[b * TT + threadIdx.x];
    counts[threadIdx.x] = s;
    c[threadIdx.x] = s;
  }
  __syncthreads();
  float s = 0.0f, q = 0.0f;
  for (int b = 0; b < STATS_GRID; ++b) {
    s += psum[b * 256 + threadIdx.x];
    q += psq[b * 256 + threadIdx.x];
  }
  float n = c[threadIdx.x >> 6];
  float m = s / n;
  mean[threadIdx.x] = m;
  stdv[threadIdx.x] = (q - s * s / n) / sqrtf(n - 1.0f);
}

// tilde = (H - mean)/std in place + bf16 copy; LDS-private histogram -> partial dump
__global__ __launch_bounds__(256) void k_tilde_hist(float* __restrict__ H,
                                                    const int* __restrict__ nt,
                                                    const float* __restrict__ mean,
                                                    const float* __restrict__ stdv,
                                                    ushortT* __restrict__ tb,
                                                    unsigned* __restrict__ pe, int NW) {
  __shared__ unsigned hist[BINS];
  for (int b = threadIdx.x; b < BINS; b += 256) hist[b] = 0;
  __syncthreads();
  for (int i = blockIdx.x * 256 + threadIdx.x; i < NW; i += HG * 256) {
    int nn = i >> 6, d = i & 63;
    int t = nt[nn];
    float v = (H[i] - mean[t * WH + d]) / stdv[t * WH + d];
    H[i] = v;
    unsigned u = __float_as_uint(v);
    tb[i] = (ushortT)((u + 0x7FFFu + ((u >> 16) & 1u)) >> 16);
    int b = (int)((v + 8.0f) * BIN_SCALE);
    b = min(max(b, 0), BINS - 1);
    atomicAdd(&hist[b], 1u);
  }
  __syncthreads();
  for (int b = threadIdx.x; b < BINS; b += 256)
    pe[(size_t)blockIdx.x * BINS + b] = hist[b];
}

__global__ __launch_bounds__(256) void k_histG(const float* __restrict__ g,
                                               unsigned* __restrict__ pg, int M) {
  __shared__ unsigned hist[BINS];
  for (int b = threadIdx.x; b < BINS; b += 256) hist[b] = 0;
  __syncthreads();
  for (int i = blockIdx.x * 256 + threadIdx.x; i < M; i += HG * 256) {
    float v = g[i];
    int b = (int)((v + 8.0f) * BIN_SCALE);
    b = min(max(b, 0), BINS - 1);
    atomicAdd(&hist[b], 1u);
  }
  __syncthreads();
  for (int b = threadIdx.x; b < BINS; b += 256)
    pg[(size_t)blockIdx.x * BINS + b] = hist[b];
}

__global__ __launch_bounds__(256) void k_diff(const unsigned* __restrict__ pg,
                                              const unsigned* __restrict__ pe,
                                              int* __restrict__ diff) {
  int b = blockIdx.x * 256 + threadIdx.x;
  int s = 0;
  for (int p = 0; p < HG; ++p)
    s += (int)pg[(size_t)p * BINS + b] - (int)pe[(size_t)p * BINS + b];
  diff[b] = s;
}

__global__ __launch_bounds__(1024) void k_wass(const int* __restrict__ diff,
                                               float* __restrict__ out, int M, int NW) {
  int tid = threadIdx.x;
  int lo = tid * (BINS / 1024);
  int d[BINS / 1024];
  int s = 0;
#pragma unroll
  for (int i = 0; i < BINS / 1024; ++i) {
    d[i] = diff[lo + i];
    s += d[i];
  }
  __shared__ int sc[1024];
  sc[tid] = s;
  __syncthreads();
  for (int st = 1; st < 1024; st <<= 1) {
    int v = (tid >= st) ? sc[tid - st] : 0;
    __syncthreads();
    sc[tid] += v;
    __syncthreads();
  }
  int run = sc[tid] - s;
  long long a = 0;
#pragma unroll
  for (int i = 0; i < BINS / 1024; ++i) {
    run += d[i];
    a += (long long)(run < 0 ? -run : run);
  }
  __shared__ long long rd[1024];
  rd[tid] = a;
  __syncthreads();
  for (int st = 512; st > 0; st >>= 1) {
    if (tid < st) rd[tid] += rd[tid + st];
    __syncthreads();
  }
  if (tid == 0) out[NW] = (float)((double)rd[0] * (1.0 / (double)BIN_SCALE) / (double)M);
}

// ---------- CSR build ----------
__global__ __launch_bounds__(256) void k_degi(const int* __restrict__ dst,
                                              unsigned* __restrict__ degi, int E) {
  int e = blockIdx.x * 256 + threadIdx.x;
  if (e < E) atomicAdd(&degi[__builtin_nontemporal_load(&dst[e])], 1u);
}

// ---------- device-wide exclusive scan, 3 phases over SB blocks ----------
__global__ __launch_bounds__(ST) void k_scan_part(const unsigned* __restrict__ in,
                                                  unsigned* __restrict__ bsum, int L) {
  int C = (L + SB * ST - 1) / (SB * ST);
  int base = (blockIdx.x * ST + threadIdx.x) * C;
  int hi = min(base + C, L);
  unsigned s = 0;
  for (int i = base; i < hi; ++i) s += in[i];
  __shared__ unsigned red[ST];
  red[threadIdx.x] = s;
  __syncthreads();
  for (int st = ST / 2; st > 0; st >>= 1) {
    if (threadIdx.x < st) red[threadIdx.x] += red[threadIdx.x + st];
    __syncthreads();
  }
  if (threadIdx.x == 0) bsum[blockIdx.x] = red[0];
}
__global__ __launch_bounds__(ST) void k_scan_mid(unsigned* __restrict__ bsum) {
  __shared__ unsigned ts[ST];
  unsigned v = (threadIdx.x < SB) ? bsum[threadIdx.x] : 0u;
  ts[threadIdx.x] = v;
  __syncthreads();
  for (int st = 1; st < ST; st <<= 1) {
    unsigned u = (threadIdx.x >= (unsigned)st) ? ts[threadIdx.x - st] : 0u;
    __syncthreads();
    ts[threadIdx.x] += u;
    __syncthreads();
  }
  if (threadIdx.x < SB) bsum[threadIdx.x] = ts[threadIdx.x] - v;
}
__global__ __launch_bounds__(ST) void k_scan_apply(const unsigned* __restrict__ in,
                                                   const unsigned* __restrict__ bsum,
                                                   unsigned* __restrict__ outp, int L) {
  int C = (L + SB * ST - 1) / (SB * ST);
  int base = (blockIdx.x * ST + threadIdx.x) * C;
  int hi = min(base + C, L);
  unsigned s = 0;
  for (int i = base; i < hi; ++i) s += in[i];
  __shared__ unsigned ts[ST];
  ts[threadIdx.x] = s;
  __syncthreads();
  for (int st = 1; st < ST; st <<= 1) {
    unsigned u = (threadIdx.x >= (unsigned)st) ? ts[threadIdx.x - st] : 0u;
    __syncthreads();
    ts[threadIdx.x] += u;
    __syncthreads();
  }
  unsigned run = bsum[blockIdx.x] + ts[threadIdx.x] - s;
  for (int i = base; i < hi; ++i) {
    unsigned c = in[i];
    outp[i] = run;
    run += c;
  }
}

// dst-range partitioned scatter: pass p handles dst in [lo,hi).
// Active esrc window ~N/BP*deg*4B = 1.6MB -> stays L2-resident, lines evict
// fully dirty once (kills the 16x write amplification seen at 107MB WRITE_SIZE).
__global__ __launch_bounds__(256) void k_build_pass(const int* __restrict__ src,
                                                    const int* __restrict__ dst,
                                                    const unsigned* __restrict__ off,
                                                    unsigned* __restrict__ cur,
                                                    unsigned* __restrict__ esrc, int E,
                                                    int lo, int hi) {
  int e = blockIdx.x * 256 + threadIdx.x;
  if (e >= E) return;
  int t = __builtin_nontemporal_load(&dst[e]);
  if (t < lo || t >= hi) return;
  int sv = __builtin_nontemporal_load(&src[e]);
  unsigned p = off[t] + atomicAdd(&cur[t], 1u);
  esrc[p] = (unsigned)sv;
}

// ---------- diffusion hop (bf16 Z) ----------
// wave per node; lane = g*8+c: 8 edge-groups, c = col-eighth (8 bf16 = 16 B per lane)
__global__ __launch_bounds__(256) void k_spmm(const unsigned* __restrict__ off,
                                              const unsigned* __restrict__ degi,
                                              const unsigned* __restrict__ esrc,
                                              const ushortT* __restrict__ Zb,
                                              const float* __restrict__ tilde,
                                              ushortT* __restrict__ Zn, int N) {
  int wv = threadIdx.x >> 6, lane = threadIdx.x & 63;
  int n = blockIdx.x * 4 + wv;
  if (n >= N) return;
  int g = lane >> 3, c = lane & 7;
  unsigned st = off[n], dg = degi[n];
  float a[8] = {};
  for (unsigned e = g; e < dg; e += 8) {
    unsigned s = esrc[st + e];
    uint4 v = *((const uint4*)(Zb + (size_t)s * WH) + c);
    a[0] += bf_lo(v.x); a[1] += bf_hi(v.x);
    a[2] += bf_lo(v.y); a[3] += bf_hi(v.y);
    a[4] += bf_lo(v.z); a[5] += bf_hi(v.z);
    a[6] += bf_lo(v.w); a[7] += bf_hi(v.w);
  }
#pragma unroll
  for (int m = 8; m <= 32; m <<= 1) {
#pragma unroll
    for (int j = 0; j < 8; ++j) a[j] += __shfl_xor(a[j], m, 64);
  }
  if (g == 0) {
    float wn = (1.0f - ALPHA_C) / fmaxf((float)dg, 1.0f);
    const float4* Tr = (const float4*)(tilde + (size_t)n * WH);
    float4 t0 = Tr[2 * c], t1 = Tr[2 * c + 1];
    float o0 = wn * a[0] + ALPHA_C * t0.x, o1 = wn * a[1] + ALPHA_C * t0.y;
    float o2 = wn * a[2] + ALPHA_C * t0.z, o3 = wn * a[3] + ALPHA_C * t0.w;
    float o4 = wn * a[4] + ALPHA_C * t1.x, o5 = wn * a[5] + ALPHA_C * t1.y;
    float o6 = wn * a[6] + ALPHA_C * t1.z, o7 = wn * a[7] + ALPHA_C * t1.w;
    uint4 p;
    p.x = pack_bf16(o0, o1);
    p.y = pack_bf16(o2, o3);
    p.z = pack_bf16(o4, o5);
    p.w = pack_bf16(o6, o7);
    *((uint4*)(Zn + (size_t)n * WH) + c) = p;
  }
}

// ---------- epilogue: denorm + row-L2 (bf16 Z in) ----------
__global__ __launch_bounds__(256) void k_final(const ushortT* __restrict__ Zb,
                                               const int* __restrict__ nt,
                                               const float* __restrict__ mean,
                                               const float* __restrict__ stdv,
                                               float* __restrict__ out, int N) {
  int wv = threadIdx.x >> 6, lane = threadIdx.x & 63;
  int n = blockIdx.x * 4 + wv;
  if (n >= N) return;
  int t = nt[n];
  float zv = __uint_as_float((unsigned)Zb[(size_t)n * WH + lane] << 16);
  float z = zv * stdv[t * WH + lane] + mean[t * WH + lane];
  float s = z * z;
#pragma unroll
  for (int off = 32; off > 0; off >>= 1) s += __shfl_xor(s, off, 64);
  float r = 1.0f / fmaxf(sqrtf(s), 1e-12f);
  out[(size_t)n * WH + lane] = z * r;
}

extern "C" void kernel_launch(void* const* d_in, const int* in_sizes, int n_in,
                              void* d_out, int out_size, void* d_ws, size_t ws_size,
                              hipStream_t stream) {
  const float* X = (const float*)d_in[0];
  const float* W = (const float*)d_in[1];
  const float* bias = (const float*)d_in[2];
  const float* g = (const float*)d_in[3];
  const int* ei = (const int*)d_in[4];
  const int* nt = (const int*)d_in[5];

  const int N = in_sizes[5];
  const int E = in_sizes[4] / 2;
  const int M = in_sizes[3];  // N * WH
  const int NW = N * WH;
  const int* srcp = ei;
  const int* dstp = ei + E;

  char* w = (char*)d_ws;
  size_t o = 0;
  auto alloc = [&](size_t bytes) {
    size_t r = o;
    o += (bytes + 255) & ~(size_t)255;
    return r;
  };
  size_t off_stats = alloc(4096);  // counts@0, mean@256, std@1280
  size_t off_psum  = alloc((size_t)STATS_GRID * 256 * 4);
  size_t off_psq   = alloc((size_t)STATS_GRID * 256 * 4);
  size_t off_pcnt  = alloc((size_t)STATS_GRID * TT * 4);
  size_t off_diff  = alloc((size_t)BINS * 4);
  size_t off_bsum  = alloc((size_t)SB * 4);
  size_t off_degi  = alloc((size_t)N * 4);  // memset region start
  size_t off_cur   = alloc((size_t)N * 4);  // memset region end (256B-aligned slot!)
  size_t off_off   = alloc((size_t)N * 4);
  size_t off_esrc  = alloc((size_t)E * 4);
  size_t off_tilde = alloc((size_t)NW * 4);
  size_t off_tbf   = alloc((size_t)NW * 2);  // bf16 tilde (hop-0 gather source)
  size_t off_bufA  = alloc((size_t)NW * 4);  // partial hists alias; later bf16 Z ping
  size_t off_bufB  = alloc((size_t)NW * 4);  // partial hists alias; later bf16 Z pong

  float* counts = (float*)(w + off_stats + 0);
  float* mean   = (float*)(w + off_stats + 256);
  float* stdv   = (float*)(w + off_stats + 1280);
  float* psum   = (float*)(w + off_psum);
  float* psq    = (float*)(w + off_psq);
  float* pcnt   = (float*)(w + off_pcnt);
  int* diff     = (int*)(w + off_diff);
  unsigned* bsum = (unsigned*)(w + off_bsum);
  unsigned* degi = (unsigned*)(w + off_degi);
  unsigned* cur  = (unsigned*)(w + off_cur);
  unsigned* offp = (unsigned*)(w + off_off);
  unsigned* esrc = (unsigned*)(w + off_esrc);
  float* tilde   = (float*)(w + off_tilde);
  ushortT* tbf   = (ushortT*)(w + off_tbf);
  unsigned* pg   = (unsigned*)(w + off_bufA);
  unsigned* pe   = (unsigned*)(w + off_bufB);
  ushortT* ZA    = (ushortT*)(w + off_bufA);
  ushortT* ZB    = (ushortT*)(w + off_bufB);
  float* out = (float*)d_out;

  // zero degree+cursor; span covers the alignment pad between slots.
  hipMemsetAsync(w + off_degi, 0, off_cur - off_degi + (size_t)N * 4, stream);

  // 1) encode + L2 norm -> tilde buffer (holds H for now)
  k_encode<<<(N + ENC_BN - 1) / ENC_BN, ENC_T, 0, stream>>>(X, W, bias, tilde, N);

  // 2) per-type stats (fused sum/sumsq/count) + reduce
  k_stats<<<STATS_GRID, 256, 0, stream>>>(tilde, nt, psum, psq, pcnt, NW);
  k_reduce_stats<<<1, 256, 0, stream>>>(psum, psq, pcnt, mean, stdv, counts);

  // 3) tilde in place (+bf16 copy) + LDS histograms
  k_tilde_hist<<<HG, 256, 0, stream>>>(tilde, nt, mean, stdv, tbf, pe, NW);
  k_histG<<<HG, 256, 0, stream>>>(g, pg, M);

  // 4) W1 = (delta/M) * sum_b |prefix(cg-ce)|
  k_diff<<<BINS / 256, 256, 0, stream>>>(pg, pe, diff);
  k_wass<<<1, 1024, 0, stream>>>(diff, out, M, NW);

  // 5) CSR build — multi-block 3-phase scan + dst-range partitioned scatter
  k_degi<<<(E + 255) / 256, 256, 0, stream>>>(dstp, degi, E);
  k_scan_part<<<SB, ST, 0, stream>>>(degi, bsum, N);
  k_scan_mid<<<1, ST, 0, stream>>>(bsum);
  k_scan_apply<<<SB, ST, 0, stream>>>(degi, bsum, offp, N);
  {
    int chunk = (N + BP - 1) / BP;
    for (int p = 0; p < BP; ++p) {
      int lo = p * chunk;
      int hi = min(lo + chunk, N);
      k_build_pass<<<(E + 255) / 256, 256, 0, stream>>>(srcp, dstp, offp, cur, esrc,
                                                        E, lo, hi);
    }
  }

  // 6) K=10 diffusion hops, bf16 ping-pong (partial hists dead now)
  const ushortT* Zc = tbf;
  for (int k = 0; k < 10; ++k) {
    ushortT* Zn = (k & 1) ? ZB : ZA;
    k_spmm<<<(N + 3) / 4, 256, 0, stream>>>(offp, degi, esrc, Zc, tilde, Zn, N);
    Zc = Zn;
  }

  // 7) denorm + row L2 -> out
  k_final<<<(N + 3) / 4, 256, 0, stream>>>(Zc, nt, mean, stdv, out, N);
}

// Round 5
// 1083.218 us; speedup vs baseline: 1.0105x; 1.0105x over previous
//
#include <hip/hip_runtime.h>
#include <math.h>

#define WH 64
#define WIN 256
#define TT 4
#define ALPHA_C 0.1f
#define STATS_GRID 256
#define KC 32
#define ENC_T 64
#define ENC_BN 32
#define XTS 36                  // 32 + 4: conflict-free a-reads, keeps 16B row align
#define BINS 16384              // bins over [-8, 8)
#define BIN_SCALE 1024.0f       // BINS / 16
#define HG 256                  // histogram grid (partial hists)
#define SB 128                  // scan blocks
#define ST 256                  // scan threads/block

typedef unsigned short ushortT;

__device__ __forceinline__ unsigned pack_bf16(float a, float b) {
  unsigned ua = __float_as_uint(a), ub = __float_as_uint(b);
  ua = (ua + 0x7FFFu + ((ua >> 16) & 1u)) >> 16;          // RNE
  ub = ((ub + 0x7FFFu + ((ub >> 16) & 1u)) >> 16) << 16;
  return (ua & 0xFFFFu) | ub;
}
__device__ __forceinline__ float bf_lo(unsigned p) { return __uint_as_float(p << 16); }
__device__ __forceinline__ float bf_hi(unsigned p) { return __uint_as_float(p & 0xFFFF0000u); }

// ---------- encode: H = l2norm_rows(X @ W + b) ----------
// 1-wave blocks (no inter-wave barriers), 32 nodes/block, 4x8 acc/thread.
// grid=3125 -> ~12 blocks/CU: staging of one block overlaps compute of others.
__global__ __launch_bounds__(64, 3) void k_encode(const float* __restrict__ X,
                                                  const float* __restrict__ W,
                                                  const float* __restrict__ bias,
                                                  float* __restrict__ H, int N) {
  __shared__ __align__(16) float XsT[KC * XTS];  // 4.6 KB
  __shared__ __align__(16) float Ws[KC * WH];    // 8 KB
  int tid = threadIdx.x;
  int ng = tid >> 3, cg = tid & 7;   // ng: 8 node-groups of 4; cg: 8 col-groups of 8
  int nodeBase = blockIdx.x * ENC_BN;
  float acc[4][8] = {};
  for (int k0 = 0; k0 < WIN; k0 += KC) {
    __syncthreads();
    // stage W chunk: KC*WH = 2048 floats = 512 float4, 8 per thread
    const float4* Wg4 = (const float4*)(W + (size_t)k0 * WH);
    float4* Ws4 = (float4*)Ws;
#pragma unroll
    for (int j = 0; j < 8; ++j) Ws4[tid + j * 64] = Wg4[tid + j * 64];
    // stage X chunk transposed: 32 nodes x 32 k = 256 float4, 4 per thread
#pragma unroll
    for (int i = 0; i < 4; ++i) {
      int idx = tid + i * 64;
      int ln = idx >> 3, f4 = idx & 7;
      int node = nodeBase + ln;
      float4 xv = (node < N)
                      ? *(const float4*)(X + (size_t)node * WIN + k0 + f4 * 4)
                      : make_float4(0.f, 0.f, 0.f, 0.f);
      float* p = &XsT[(f4 * 4) * XTS + ln];
      p[0] = xv.x;
      p[XTS] = xv.y;
      p[2 * XTS] = xv.z;
      p[3 * XTS] = xv.w;
    }
    __syncthreads();
#pragma unroll 8
    for (int k = 0; k < KC; ++k) {
      float4 a0 = *(const float4*)&XsT[k * XTS + ng * 4];
      float4 b0 = *(const float4*)&Ws[k * WH + cg * 8];
      float4 b1 = *(const float4*)&Ws[k * WH + cg * 8 + 4];
      float av[4] = {a0.x, a0.y, a0.z, a0.w};
      float bb[8] = {b0.x, b0.y, b0.z, b0.w, b1.x, b1.y, b1.z, b1.w};
#pragma unroll
      for (int i = 0; i < 4; ++i)
#pragma unroll
        for (int j = 0; j < 8; ++j) acc[i][j] += av[i] * bb[j];
    }
  }
  float4 bb0 = *(const float4*)(bias + cg * 8);
  float4 bb1 = *(const float4*)(bias + cg * 8 + 4);
  float bv[8] = {bb0.x, bb0.y, bb0.z, bb0.w, bb1.x, bb1.y, bb1.z, bb1.w};
#pragma unroll
  for (int i = 0; i < 4; ++i) {
    float h[8];
    float s = 0.f;
#pragma unroll
    for (int j = 0; j < 8; ++j) {
      h[j] = acc[i][j] + bv[j];
      s += h[j] * h[j];
    }
    s += __shfl_xor(s, 1, 64);
    s += __shfl_xor(s, 2, 64);
    s += __shfl_xor(s, 4, 64);
    float r = 1.0f / fmaxf(sqrtf(s), 1e-12f);
    int node = nodeBase + ng * 4 + i;
    if (node < N) {
      float4 o0 = {h[0] * r, h[1] * r, h[2] * r, h[3] * r};
      float4 o1 = {h[4] * r, h[5] * r, h[6] * r, h[7] * r};
      *(float4*)(H + (size_t)node * WH + cg * 8) = o0;
      *(float4*)(H + (size_t)node * WH + cg * 8 + 4) = o1;
    }
  }
}

// ---------- per-type stats: fused sum + sumsq + counts ----------
__global__ __launch_bounds__(256) void k_stats(const float* __restrict__ H,
                                               const int* __restrict__ nt,
                                               float* __restrict__ psum,
                                               float* __restrict__ psq,
                                               float* __restrict__ pcnt, int NW) {
  __shared__ float ls[TT * WH], ls2[TT * WH];
  __shared__ float lc[TT];
  ls[threadIdx.x] = 0.0f;
  ls2[threadIdx.x] = 0.0f;
  if (threadIdx.x < TT) lc[threadIdx.x] = 0.0f;
  __syncthreads();
  for (int i = blockIdx.x * 256 + threadIdx.x; i < NW; i += STATS_GRID * 256) {
    int nn = i >> 6, d = i & 63;
    int t = nt[nn];
    float v = H[i];
    atomicAdd(&ls[t * WH + d], v);
    atomicAdd(&ls2[t * WH + d], v * v);
    if (d == 0) atomicAdd(&lc[t], 1.0f);
  }
  __syncthreads();
  psum[blockIdx.x * 256 + threadIdx.x] = ls[threadIdx.x];
  psq[blockIdx.x * 256 + threadIdx.x] = ls2[threadIdx.x];
  if (threadIdx.x < TT) pcnt[blockIdx.x * TT + threadIdx.x] = lc[threadIdx.x];
}

__global__ __launch_bounds__(256) void k_reduce_stats(const float* __restrict__ psum,
                                                      const float* __restrict__ psq,
                                                      const float* __restrict__ pcnt,
                                                      float* __restrict__ mean,
                                                      float* __restrict__ stdv,
                                                      float* __restrict__ counts) {
  __shared__ float c[TT];
  if (threadIdx.x < TT) {
    float s = 0.0f;
    for (int b = 0; b < STATS_GRID; ++b) s += pcnt[b * TT + threadIdx.x];
    counts[threadIdx.x] = s;
    c[threadIdx.x] = s;
  }
  __syncthreads();
  float s = 0.0f, q = 0.0f;
  for (int b = 0; b < STATS_GRID; ++b) {
    s += psum[b * 256 + threadIdx.x];
    q += psq[b * 256 + threadIdx.x];
  }
  float n = c[threadIdx.x >> 6];
  float m = s / n;
  mean[threadIdx.x] = m;
  stdv[threadIdx.x] = (q - s * s / n) / sqrtf(n - 1.0f);
}

// tilde = (H - mean)/std in place + bf16 copy; LDS-private histogram -> partial dump
__global__ __launch_bounds__(256) void k_tilde_hist(float* __restrict__ H,
                                                    const int* __restrict__ nt,
                                                    const float* __restrict__ mean,
                                                    const float* __restrict__ stdv,
                                                    ushortT* __restrict__ tb,
                                                    unsigned* __restrict__ pe, int NW) {
  __shared__ unsigned hist[BINS];
  for (int b = threadIdx.x; b < BINS; b += 256) hist[b] = 0;
  __syncthreads();
  for (int i = blockIdx.x * 256 + threadIdx.x; i < NW; i += HG * 256) {
    int nn = i >> 6, d = i & 63;
    int t = nt[nn];
    float v = (H[i] - mean[t * WH + d]) / stdv[t * WH + d];
    H[i] = v;
    unsigned u = __float_as_uint(v);
    tb[i] = (ushortT)((u + 0x7FFFu + ((u >> 16) & 1u)) >> 16);
    int b = (int)((v + 8.0f) * BIN_SCALE);
    b = min(max(b, 0), BINS - 1);
    atomicAdd(&hist[b], 1u);
  }
  __syncthreads();
  for (int b = threadIdx.x; b < BINS; b += 256)
    pe[(size_t)blockIdx.x * BINS + b] = hist[b];
}

__global__ __launch_bounds__(256) void k_histG(const float* __restrict__ g,
                                               unsigned* __restrict__ pg, int M) {
  __shared__ unsigned hist[BINS];
  for (int b = threadIdx.x; b < BINS; b += 256) hist[b] = 0;
  __syncthreads();
  for (int i = blockIdx.x * 256 + threadIdx.x; i < M; i += HG * 256) {
    float v = g[i];
    int b = (int)((v + 8.0f) * BIN_SCALE);
    b = min(max(b, 0), BINS - 1);
    atomicAdd(&hist[b], 1u);
  }
  __syncthreads();
  for (int b = threadIdx.x; b < BINS; b += 256)
    pg[(size_t)blockIdx.x * BINS + b] = hist[b];
}

__global__ __launch_bounds__(256) void k_diff(const unsigned* __restrict__ pg,
                                              const unsigned* __restrict__ pe,
                                              int* __restrict__ diff) {
  int b = blockIdx.x * 256 + threadIdx.x;
  int s = 0;
  for (int p = 0; p < HG; ++p)
    s += (int)pg[(size_t)p * BINS + b] - (int)pe[(size_t)p * BINS + b];
  diff[b] = s;
}

__global__ __launch_bounds__(1024) void k_wass(const int* __restrict__ diff,
                                               float* __restrict__ out, int M, int NW) {
  int tid = threadIdx.x;
  int lo = tid * (BINS / 1024);
  int d[BINS / 1024];
  int s = 0;
#pragma unroll
  for (int i = 0; i < BINS / 1024; ++i) {
    d[i] = diff[lo + i];
    s += d[i];
  }
  __shared__ int sc[1024];
  sc[tid] = s;
  __syncthreads();
  for (int st = 1; st < 1024; st <<= 1) {
    int v = (tid >= st) ? sc[tid - st] : 0;
    __syncthreads();
    sc[tid] += v;
    __syncthreads();
  }
  int run = sc[tid] - s;
  long long a = 0;
#pragma unroll
  for (int i = 0; i < BINS / 1024; ++i) {
    run += d[i];
    a += (long long)(run < 0 ? -run : run);
  }
  __shared__ long long rd[1024];
  rd[tid] = a;
  __syncthreads();
  for (int st = 512; st > 0; st >>= 1) {
    if (tid < st) rd[tid] += rd[tid + st];
    __syncthreads();
  }
  if (tid == 0) out[NW] = (float)((double)rd[0] * (1.0 / (double)BIN_SCALE) / (double)M);
}

// ---------- CSR build ----------
__global__ __launch_bounds__(256) void k_degi(const int* __restrict__ dst,
                                              unsigned* __restrict__ degi, int E) {
  int e = blockIdx.x * 256 + threadIdx.x;
  if (e < E) atomicAdd(&degi[dst[e]], 1u);
}

// ---------- device-wide exclusive scan, 3 phases over SB blocks ----------
__global__ __launch_bounds__(ST) void k_scan_part(const unsigned* __restrict__ in,
                                                  unsigned* __restrict__ bsum, int L) {
  int C = (L + SB * ST - 1) / (SB * ST);
  int base = (blockIdx.x * ST + threadIdx.x) * C;
  int hi = min(base + C, L);
  unsigned s = 0;
  for (int i = base; i < hi; ++i) s += in[i];
  __shared__ unsigned red[ST];
  red[threadIdx.x] = s;
  __syncthreads();
  for (int st = ST / 2; st > 0; st >>= 1) {
    if (threadIdx.x < st) red[threadIdx.x] += red[threadIdx.x + st];
    __syncthreads();
  }
  if (threadIdx.x == 0) bsum[blockIdx.x] = red[0];
}
__global__ __launch_bounds__(ST) void k_scan_mid(unsigned* __restrict__ bsum) {
  __shared__ unsigned ts[ST];
  unsigned v = (threadIdx.x < SB) ? bsum[threadIdx.x] : 0u;
  ts[threadIdx.x] = v;
  __syncthreads();
  for (int st = 1; st < ST; st <<= 1) {
    unsigned u = (threadIdx.x >= (unsigned)st) ? ts[threadIdx.x - st] : 0u;
    __syncthreads();
    ts[threadIdx.x] += u;
    __syncthreads();
  }
  if (threadIdx.x < SB) bsum[threadIdx.x] = ts[threadIdx.x] - v;
}
__global__ __launch_bounds__(ST) void k_scan_apply(const unsigned* __restrict__ in,
                                                   const unsigned* __restrict__ bsum,
                                                   unsigned* __restrict__ outp, int L) {
  int C = (L + SB * ST - 1) / (SB * ST);
  int base = (blockIdx.x * ST + threadIdx.x) * C;
  int hi = min(base + C, L);
  unsigned s = 0;
  for (int i = base; i < hi; ++i) s += in[i];
  __shared__ unsigned ts[ST];
  ts[threadIdx.x] = s;
  __syncthreads();
  for (int st = 1; st < ST; st <<= 1) {
    unsigned u = (threadIdx.x >= (unsigned)st) ? ts[threadIdx.x - st] : 0u;
    __syncthreads();
    ts[threadIdx.x] += u;
    __syncthreads();
  }
  unsigned run = bsum[blockIdx.x] + ts[threadIdx.x] - s;
  for (int i = base; i < hi; ++i) {
    unsigned c = in[i];
    outp[i] = run;
    run += c;
  }
}

// single-pass scatter (measured faster than dst-partitioned 4-pass: latency-
// bound, not write-BW-bound -- R4 post-mortem)
__global__ __launch_bounds__(256) void k_build(const int* __restrict__ src,
                                               const int* __restrict__ dst,
                                               const unsigned* __restrict__ off,
                                               unsigned* __restrict__ cur,
                                               unsigned* __restrict__ esrc, int E) {
  int e = blockIdx.x * 256 + threadIdx.x;
  if (e >= E) return;
  int t = dst[e];
  unsigned p = off[t] + atomicAdd(&cur[t], 1u);
  esrc[p] = (unsigned)src[e];
}

// ---------- diffusion hop (bf16 Z) ----------
// wave per node; lane = g*8+c: 8 edge-groups, c = col-eighth (8 bf16 = 16 B per lane)
__global__ __launch_bounds__(256) void k_spmm(const unsigned* __restrict__ off,
                                              const unsigned* __restrict__ degi,
                                              const unsigned* __restrict__ esrc,
                                              const ushortT* __restrict__ Zb,
                                              const float* __restrict__ tilde,
                                              ushortT* __restrict__ Zn, int N) {
  int wv = threadIdx.x >> 6, lane = threadIdx.x & 63;
  int n = blockIdx.x * 4 + wv;
  if (n >= N) return;
  int g = lane >> 3, c = lane & 7;
  unsigned st = off[n], dg = degi[n];
  float a[8] = {};
  for (unsigned e = g; e < dg; e += 8) {
    unsigned s = esrc[st + e];
    uint4 v = *((const uint4*)(Zb + (size_t)s * WH) + c);
    a[0] += bf_lo(v.x); a[1] += bf_hi(v.x);
    a[2] += bf_lo(v.y); a[3] += bf_hi(v.y);
    a[4] += bf_lo(v.z); a[5] += bf_hi(v.z);
    a[6] += bf_lo(v.w); a[7] += bf_hi(v.w);
  }
#pragma unroll
  for (int m = 8; m <= 32; m <<= 1) {
#pragma unroll
    for (int j = 0; j < 8; ++j) a[j] += __shfl_xor(a[j], m, 64);
  }
  if (g == 0) {
    float wn = (1.0f - ALPHA_C) / fmaxf((float)dg, 1.0f);
    const float4* Tr = (const float4*)(tilde + (size_t)n * WH);
    float4 t0 = Tr[2 * c], t1 = Tr[2 * c + 1];
    float o0 = wn * a[0] + ALPHA_C * t0.x, o1 = wn * a[1] + ALPHA_C * t0.y;
    float o2 = wn * a[2] + ALPHA_C * t0.z, o3 = wn * a[3] + ALPHA_C * t0.w;
    float o4 = wn * a[4] + ALPHA_C * t1.x, o5 = wn * a[5] + ALPHA_C * t1.y;
    float o6 = wn * a[6] + ALPHA_C * t1.z, o7 = wn * a[7] + ALPHA_C * t1.w;
    uint4 p;
    p.x = pack_bf16(o0, o1);
    p.y = pack_bf16(o2, o3);
    p.z = pack_bf16(o4, o5);
    p.w = pack_bf16(o6, o7);
    *((uint4*)(Zn + (size_t)n * WH) + c) = p;
  }
}

// ---------- epilogue: denorm + row-L2 (bf16 Z in) ----------
__global__ __launch_bounds__(256) void k_final(const ushortT* __restrict__ Zb,
                                               const int* __restrict__ nt,
                                               const float* __restrict__ mean,
                                               const float* __restrict__ stdv,
                                               float* __restrict__ out, int N) {
  int wv = threadIdx.x >> 6, lane = threadIdx.x & 63;
  int n = blockIdx.x * 4 + wv;
  if (n >= N) return;
  int t = nt[n];
  float zv = __uint_as_float((unsigned)Zb[(size_t)n * WH + lane] << 16);
  float z = zv * stdv[t * WH + lane] + mean[t * WH + lane];
  float s = z * z;
#pragma unroll
  for (int off = 32; off > 0; off >>= 1) s += __shfl_xor(s, off, 64);
  float r = 1.0f / fmaxf(sqrtf(s), 1e-12f);
  out[(size_t)n * WH + lane] = z * r;
}

extern "C" void kernel_launch(void* const* d_in, const int* in_sizes, int n_in,
                              void* d_out, int out_size, void* d_ws, size_t ws_size,
                              hipStream_t stream) {
  const float* X = (const float*)d_in[0];
  const float* W = (const float*)d_in[1];
  const float* bias = (const float*)d_in[2];
  const float* g = (const float*)d_in[3];
  const int* ei = (const int*)d_in[4];
  const int* nt = (const int*)d_in[5];

  const int N = in_sizes[5];
  const int E = in_sizes[4] / 2;
  const int M = in_sizes[3];  // N * WH
  const int NW = N * WH;
  const int* srcp = ei;
  const int* dstp = ei + E;

  char* w = (char*)d_ws;
  size_t o = 0;
  auto alloc = [&](size_t bytes) {
    size_t r = o;
    o += (bytes + 255) & ~(size_t)255;
    return r;
  };
  size_t off_stats = alloc(4096);  // counts@0, mean@256, std@1280
  size_t off_psum  = alloc((size_t)STATS_GRID * 256 * 4);
  size_t off_psq   = alloc((size_t)STATS_GRID * 256 * 4);
  size_t off_pcnt  = alloc((size_t)STATS_GRID * TT * 4);
  size_t off_diff  = alloc((size_t)BINS * 4);
  size_t off_bsum  = alloc((size_t)SB * 4);
  size_t off_degi  = alloc((size_t)N * 4);  // memset region start
  size_t off_cur   = alloc((size_t)N * 4);  // memset region end (256B-aligned slot!)
  size_t off_off   = alloc((size_t)N * 4);
  size_t off_esrc  = alloc((size_t)E * 4);
  size_t off_tilde = alloc((size_t)NW * 4);
  size_t off_tbf   = alloc((size_t)NW * 2);  // bf16 tilde (hop-0 gather source)
  size_t off_bufA  = alloc((size_t)NW * 4);  // partial hists alias; later bf16 Z ping
  size_t off_bufB  = alloc((size_t)NW * 4);  // partial hists alias; later bf16 Z pong

  float* counts = (float*)(w + off_stats + 0);
  float* mean   = (float*)(w + off_stats + 256);
  float* stdv   = (float*)(w + off_stats + 1280);
  float* psum   = (float*)(w + off_psum);
  float* psq    = (float*)(w + off_psq);
  float* pcnt   = (float*)(w + off_pcnt);
  int* diff     = (int*)(w + off_diff);
  unsigned* bsum = (unsigned*)(w + off_bsum);
  unsigned* degi = (unsigned*)(w + off_degi);
  unsigned* cur  = (unsigned*)(w + off_cur);
  unsigned* offp = (unsigned*)(w + off_off);
  unsigned* esrc = (unsigned*)(w + off_esrc);
  float* tilde   = (float*)(w + off_tilde);
  ushortT* tbf   = (ushortT*)(w + off_tbf);
  unsigned* pg   = (unsigned*)(w + off_bufA);
  unsigned* pe   = (unsigned*)(w + off_bufB);
  ushortT* ZA    = (ushortT*)(w + off_bufA);
  ushortT* ZB    = (ushortT*)(w + off_bufB);
  float* out = (float*)d_out;

  // zero degree+cursor; span covers the alignment pad between slots.
  hipMemsetAsync(w + off_degi, 0, off_cur - off_degi + (size_t)N * 4, stream);

  // 1) encode + L2 norm -> tilde buffer (holds H for now)
  k_encode<<<(N + ENC_BN - 1) / ENC_BN, ENC_T, 0, stream>>>(X, W, bias, tilde, N);

  // 2) per-type stats (fused sum/sumsq/count) + reduce
  k_stats<<<STATS_GRID, 256, 0, stream>>>(tilde, nt, psum, psq, pcnt, NW);
  k_reduce_stats<<<1, 256, 0, stream>>>(psum, psq, pcnt, mean, stdv, counts);

  // 3) tilde in place (+bf16 copy) + LDS histograms
  k_tilde_hist<<<HG, 256, 0, stream>>>(tilde, nt, mean, stdv, tbf, pe, NW);
  k_histG<<<HG, 256, 0, stream>>>(g, pg, M);

  // 4) W1 = (delta/M) * sum_b |prefix(cg-ce)|
  k_diff<<<BINS / 256, 256, 0, stream>>>(pg, pe, diff);
  k_wass<<<1, 1024, 0, stream>>>(diff, out, M, NW);

  // 5) CSR build — multi-block 3-phase scan + single-pass scatter
  k_degi<<<(E + 255) / 256, 256, 0, stream>>>(dstp, degi, E);
  k_scan_part<<<SB, ST, 0, stream>>>(degi, bsum, N);
  k_scan_mid<<<1, ST, 0, stream>>>(bsum);
  k_scan_apply<<<SB, ST, 0, stream>>>(degi, bsum, offp, N);
  k_build<<<(E + 255) / 256, 256, 0, stream>>>(srcp, dstp, offp, cur, esrc, E);

  // 6) K=10 diffusion hops, bf16 ping-pong (partial hists dead now)
  const ushortT* Zc = tbf;
  for (int k = 0; k < 10; ++k) {
    ushortT* Zn = (k & 1) ? ZB : ZA;
    k_spmm<<<(N + 3) / 4, 256, 0, stream>>>(offp, degi, esrc, Zc, tilde, Zn, N);
    Zc = Zn;
  }

  // 7) denorm + row L2 -> out
  k_final<<<(N + 3) / 4, 256, 0, stream>>>(Zc, nt, mean, stdv, out, N);
}

// Round 6
// 1011.756 us; speedup vs baseline: 1.0818x; 1.0706x over previous
//
#include <hip/hip_runtime.h>
#include <math.h>

#define WH 64
#define WIN 256
#define TT 4
#define ALPHA_C 0.1f
#define STATS_GRID 256
#define KC 32
#define ENC_T 64
#define ENC_BN 32
#define XTS 36                  // 32 + 4: conflict-free a-reads, keeps 16B row align
#define BINS 16384              // bins over [-8, 8)
#define BIN_SCALE 1024.0f       // BINS / 16
#define HG 256                  // histogram grid (partial hists)
#define SB 128                  // scan blocks
#define ST 256                  // scan threads/block

typedef unsigned short ushortT;

__device__ __forceinline__ unsigned pack_bf16(float a, float b) {
  unsigned ua = __float_as_uint(a), ub = __float_as_uint(b);
  ua = (ua + 0x7FFFu + ((ua >> 16) & 1u)) >> 16;          // RNE
  ub = ((ub + 0x7FFFu + ((ub >> 16) & 1u)) >> 16) << 16;
  return (ua & 0xFFFFu) | ub;
}
__device__ __forceinline__ float bf_lo(unsigned p) { return __uint_as_float(p << 16); }
__device__ __forceinline__ float bf_hi(unsigned p) { return __uint_as_float(p & 0xFFFF0000u); }

// ---------- encode: H = l2norm_rows(X @ W + b) ----------
// 1-wave blocks (no inter-wave barriers), 32 nodes/block, 4x8 acc/thread.
__global__ __launch_bounds__(64, 3) void k_encode(const float* __restrict__ X,
                                                  const float* __restrict__ W,
                                                  const float* __restrict__ bias,
                                                  float* __restrict__ H, int N) {
  __shared__ __align__(16) float XsT[KC * XTS];  // 4.6 KB
  __shared__ __align__(16) float Ws[KC * WH];    // 8 KB
  int tid = threadIdx.x;
  int ng = tid >> 3, cg = tid & 7;   // ng: 8 node-groups of 4; cg: 8 col-groups of 8
  int nodeBase = blockIdx.x * ENC_BN;
  float acc[4][8] = {};
  for (int k0 = 0; k0 < WIN; k0 += KC) {
    __syncthreads();
    // stage W chunk: KC*WH = 2048 floats = 512 float4, 8 per thread
    const float4* Wg4 = (const float4*)(W + (size_t)k0 * WH);
    float4* Ws4 = (float4*)Ws;
#pragma unroll
    for (int j = 0; j < 8; ++j) Ws4[tid + j * 64] = Wg4[tid + j * 64];
    // stage X chunk transposed: 32 nodes x 32 k = 256 float4, 4 per thread
#pragma unroll
    for (int i = 0; i < 4; ++i) {
      int idx = tid + i * 64;
      int ln = idx >> 3, f4 = idx & 7;
      int node = nodeBase + ln;
      float4 xv = (node < N)
                      ? *(const float4*)(X + (size_t)node * WIN + k0 + f4 * 4)
                      : make_float4(0.f, 0.f, 0.f, 0.f);
      float* p = &XsT[(f4 * 4) * XTS + ln];
      p[0] = xv.x;
      p[XTS] = xv.y;
      p[2 * XTS] = xv.z;
      p[3 * XTS] = xv.w;
    }
    __syncthreads();
#pragma unroll 8
    for (int k = 0; k < KC; ++k) {
      float4 a0 = *(const float4*)&XsT[k * XTS + ng * 4];
      float4 b0 = *(const float4*)&Ws[k * WH + cg * 8];
      float4 b1 = *(const float4*)&Ws[k * WH + cg * 8 + 4];
      float av[4] = {a0.x, a0.y, a0.z, a0.w};
      float bb[8] = {b0.x, b0.y, b0.z, b0.w, b1.x, b1.y, b1.z, b1.w};
#pragma unroll
      for (int i = 0; i < 4; ++i)
#pragma unroll
        for (int j = 0; j < 8; ++j) acc[i][j] += av[i] * bb[j];
    }
  }
  float4 bb0 = *(const float4*)(bias + cg * 8);
  float4 bb1 = *(const float4*)(bias + cg * 8 + 4);
  float bv[8] = {bb0.x, bb0.y, bb0.z, bb0.w, bb1.x, bb1.y, bb1.z, bb1.w};
#pragma unroll
  for (int i = 0; i < 4; ++i) {
    float h[8];
    float s = 0.f;
#pragma unroll
    for (int j = 0; j < 8; ++j) {
      h[j] = acc[i][j] + bv[j];
      s += h[j] * h[j];
    }
    s += __shfl_xor(s, 1, 64);
    s += __shfl_xor(s, 2, 64);
    s += __shfl_xor(s, 4, 64);
    float r = 1.0f / fmaxf(sqrtf(s), 1e-12f);
    int node = nodeBase + ng * 4 + i;
    if (node < N) {
      float4 o0 = {h[0] * r, h[1] * r, h[2] * r, h[3] * r};
      float4 o1 = {h[4] * r, h[5] * r, h[6] * r, h[7] * r};
      *(float4*)(H + (size_t)node * WH + cg * 8) = o0;
      *(float4*)(H + (size_t)node * WH + cg * 8 + 4) = o1;
    }
  }
}

// ---------- per-type stats: fused sum + sumsq + counts ----------
__global__ __launch_bounds__(256) void k_stats(const float* __restrict__ H,
                                               const int* __restrict__ nt,
                                               float* __restrict__ psum,
                                               float* __restrict__ psq,
                                               float* __restrict__ pcnt, int NW) {
  __shared__ float ls[TT * WH], ls2[TT * WH];
  __shared__ float lc[TT];
  ls[threadIdx.x] = 0.0f;
  ls2[threadIdx.x] = 0.0f;
  if (threadIdx.x < TT) lc[threadIdx.x] = 0.0f;
  __syncthreads();
  for (int i = blockIdx.x * 256 + threadIdx.x; i < NW; i += STATS_GRID * 256) {
    int nn = i >> 6, d = i & 63;
    int t = nt[nn];
    float v = H[i];
    atomicAdd(&ls[t * WH + d], v);
    atomicAdd(&ls2[t * WH + d], v * v);
    if (d == 0) atomicAdd(&lc[t], 1.0f);
  }
  __syncthreads();
  psum[blockIdx.x * 256 + threadIdx.x] = ls[threadIdx.x];
  psq[blockIdx.x * 256 + threadIdx.x] = ls2[threadIdx.x];
  if (threadIdx.x < TT) pcnt[blockIdx.x * TT + threadIdx.x] = lc[threadIdx.x];
}

__global__ __launch_bounds__(256) void k_reduce_stats(const float* __restrict__ psum,
                                                      const float* __restrict__ psq,
                                                      const float* __restrict__ pcnt,
                                                      float* __restrict__ mean,
                                                      float* __restrict__ stdv,
                                                      float* __restrict__ counts) {
  __shared__ float c[TT];
  if (threadIdx.x < TT) {
    float s = 0.0f;
    for (int b = 0; b < STATS_GRID; ++b) s += pcnt[b * TT + threadIdx.x];
    counts[threadIdx.x] = s;
    c[threadIdx.x] = s;
  }
  __syncthreads();
  float s = 0.0f, q = 0.0f;
  for (int b = 0; b < STATS_GRID; ++b) {
    s += psum[b * 256 + threadIdx.x];
    q += psq[b * 256 + threadIdx.x];
  }
  float n = c[threadIdx.x >> 6];
  float m = s / n;
  mean[threadIdx.x] = m;
  stdv[threadIdx.x] = (q - s * s / n) / sqrtf(n - 1.0f);
}

// tilde = (H - mean)/std in place + bf16 copy; LDS-private histogram -> partial dump
__global__ __launch_bounds__(256) void k_tilde_hist(float* __restrict__ H,
                                                    const int* __restrict__ nt,
                                                    const float* __restrict__ mean,
                                                    const float* __restrict__ stdv,
                                                    ushortT* __restrict__ tb,
                                                    unsigned* __restrict__ pe, int NW) {
  __shared__ unsigned hist[BINS];
  for (int b = threadIdx.x; b < BINS; b += 256) hist[b] = 0;
  __syncthreads();
  for (int i = blockIdx.x * 256 + threadIdx.x; i < NW; i += HG * 256) {
    int nn = i >> 6, d = i & 63;
    int t = nt[nn];
    float v = (H[i] - mean[t * WH + d]) / stdv[t * WH + d];
    H[i] = v;
    unsigned u = __float_as_uint(v);
    tb[i] = (ushortT)((u + 0x7FFFu + ((u >> 16) & 1u)) >> 16);
    int b = (int)((v + 8.0f) * BIN_SCALE);
    b = min(max(b, 0), BINS - 1);
    atomicAdd(&hist[b], 1u);
  }
  __syncthreads();
  for (int b = threadIdx.x; b < BINS; b += 256)
    pe[(size_t)blockIdx.x * BINS + b] = hist[b];
}

__global__ __launch_bounds__(256) void k_histG(const float* __restrict__ g,
                                               unsigned* __restrict__ pg, int M) {
  __shared__ unsigned hist[BINS];
  for (int b = threadIdx.x; b < BINS; b += 256) hist[b] = 0;
  __syncthreads();
  for (int i = blockIdx.x * 256 + threadIdx.x; i < M; i += HG * 256) {
    float v = g[i];
    int b = (int)((v + 8.0f) * BIN_SCALE);
    b = min(max(b, 0), BINS - 1);
    atomicAdd(&hist[b], 1u);
  }
  __syncthreads();
  for (int b = threadIdx.x; b < BINS; b += 256)
    pg[(size_t)blockIdx.x * BINS + b] = hist[b];
}

__global__ __launch_bounds__(256) void k_diff(const unsigned* __restrict__ pg,
                                              const unsigned* __restrict__ pe,
                                              int* __restrict__ diff) {
  int b = blockIdx.x * 256 + threadIdx.x;
  int s = 0;
  for (int p = 0; p < HG; ++p)
    s += (int)pg[(size_t)p * BINS + b] - (int)pe[(size_t)p * BINS + b];
  diff[b] = s;
}

__global__ __launch_bounds__(1024) void k_wass(const int* __restrict__ diff,
                                               float* __restrict__ out, int M, int NW) {
  int tid = threadIdx.x;
  int lo = tid * (BINS / 1024);
  int d[BINS / 1024];
  int s = 0;
#pragma unroll
  for (int i = 0; i < BINS / 1024; ++i) {
    d[i] = diff[lo + i];
    s += d[i];
  }
  __shared__ int sc[1024];
  sc[tid] = s;
  __syncthreads();
  for (int st = 1; st < 1024; st <<= 1) {
    int v = (tid >= st) ? sc[tid - st] : 0;
    __syncthreads();
    sc[tid] += v;
    __syncthreads();
  }
  int run = sc[tid] - s;
  long long a = 0;
#pragma unroll
  for (int i = 0; i < BINS / 1024; ++i) {
    run += d[i];
    a += (long long)(run < 0 ? -run : run);
  }
  __shared__ long long rd[1024];
  rd[tid] = a;
  __syncthreads();
  for (int st = 512; st > 0; st >>= 1) {
    if (tid < st) rd[tid] += rd[tid + st];
    __syncthreads();
  }
  if (tid == 0) out[NW] = (float)((double)rd[0] * (1.0 / (double)BIN_SCALE) / (double)M);
}

// ---------- CSR build ----------
__global__ __launch_bounds__(256) void k_degi(const int* __restrict__ dst,
                                              unsigned* __restrict__ degi, int E) {
  int e = blockIdx.x * 256 + threadIdx.x;
  if (e < E) atomicAdd(&degi[dst[e]], 1u);
}

// ---------- device-wide exclusive scan, 3 phases over SB blocks ----------
__global__ __launch_bounds__(ST) void k_scan_part(const unsigned* __restrict__ in,
                                                  unsigned* __restrict__ bsum, int L) {
  int C = (L + SB * ST - 1) / (SB * ST);
  int base = (blockIdx.x * ST + threadIdx.x) * C;
  int hi = min(base + C, L);
  unsigned s = 0;
  for (int i = base; i < hi; ++i) s += in[i];
  __shared__ unsigned red[ST];
  red[threadIdx.x] = s;
  __syncthreads();
  for (int st = ST / 2; st > 0; st >>= 1) {
    if (threadIdx.x < st) red[threadIdx.x] += red[threadIdx.x + st];
    __syncthreads();
  }
  if (threadIdx.x == 0) bsum[blockIdx.x] = red[0];
}
__global__ __launch_bounds__(ST) void k_scan_mid(unsigned* __restrict__ bsum) {
  __shared__ unsigned ts[ST];
  unsigned v = (threadIdx.x < SB) ? bsum[threadIdx.x] : 0u;
  ts[threadIdx.x] = v;
  __syncthreads();
  for (int st = 1; st < ST; st <<= 1) {
    unsigned u = (threadIdx.x >= (unsigned)st) ? ts[threadIdx.x - st] : 0u;
    __syncthreads();
    ts[threadIdx.x] += u;
    __syncthreads();
  }
  if (threadIdx.x < SB) bsum[threadIdx.x] = ts[threadIdx.x] - v;
}
__global__ __launch_bounds__(ST) void k_scan_apply(const unsigned* __restrict__ in,
                                                   const unsigned* __restrict__ bsum,
                                                   unsigned* __restrict__ outp, int L) {
  int C = (L + SB * ST - 1) / (SB * ST);
  int base = (blockIdx.x * ST + threadIdx.x) * C;
  int hi = min(base + C, L);
  unsigned s = 0;
  for (int i = base; i < hi; ++i) s += in[i];
  __shared__ unsigned ts[ST];
  ts[threadIdx.x] = s;
  __syncthreads();
  for (int st = 1; st < ST; st <<= 1) {
    unsigned u = (threadIdx.x >= (unsigned)st) ? ts[threadIdx.x - st] : 0u;
    __syncthreads();
    ts[threadIdx.x] += u;
    __syncthreads();
  }
  unsigned run = bsum[blockIdx.x] + ts[threadIdx.x] - s;
  for (int i = base; i < hi; ++i) {
    unsigned c = in[i];
    outp[i] = run;
    run += c;
  }
}

// single-pass scatter (measured faster than dst-partitioned 4-pass: latency-
// bound, not write-BW-bound -- R4 post-mortem)
__global__ __launch_bounds__(256) void k_build(const int* __restrict__ src,
                                               const int* __restrict__ dst,
                                               const unsigned* __restrict__ off,
                                               unsigned* __restrict__ cur,
                                               unsigned* __restrict__ esrc, int E) {
  int e = blockIdx.x * 256 + threadIdx.x;
  if (e >= E) return;
  int t = dst[e];
  unsigned p = off[t] + atomicAdd(&cur[t], 1u);
  esrc[p] = (unsigned)src[e];
}

// ---------- diffusion hop (bf16 Z) ----------
// 8 lanes per node (c = col-eighth), 8 nodes per wave, 32 per block.
// Zero cross-lane shuffles: each lane serially accumulates its column-eighth
// over all deg edges; epilogue uses all 64 lanes. Same gather pattern as
// before (wave touches 8 random 128B rows per iter).
__global__ __launch_bounds__(256) void k_spmm(const unsigned* __restrict__ off,
                                              const unsigned* __restrict__ degi,
                                              const unsigned* __restrict__ esrc,
                                              const ushortT* __restrict__ Zb,
                                              const float* __restrict__ tilde,
                                              ushortT* __restrict__ Zn, int N) {
  int lane = threadIdx.x & 63, wv = threadIdx.x >> 6;
  int j = lane >> 3, c = lane & 7;   // j: node slot, c: col-eighth
  int n = blockIdx.x * 32 + wv * 8 + j;
  if (n >= N) return;
  unsigned st = off[n], dg = degi[n];
  float a[8] = {};
  for (unsigned e = 0; e < dg; ++e) {
    unsigned s = esrc[st + e];
    uint4 v = *((const uint4*)(Zb + (size_t)s * WH) + c);
    a[0] += bf_lo(v.x); a[1] += bf_hi(v.x);
    a[2] += bf_lo(v.y); a[3] += bf_hi(v.y);
    a[4] += bf_lo(v.z); a[5] += bf_hi(v.z);
    a[6] += bf_lo(v.w); a[7] += bf_hi(v.w);
  }
  float wn = (1.0f - ALPHA_C) / fmaxf((float)dg, 1.0f);
  const float4* Tr = (const float4*)(tilde + (size_t)n * WH);
  float4 t0 = Tr[2 * c], t1 = Tr[2 * c + 1];
  float o0 = wn * a[0] + ALPHA_C * t0.x, o1 = wn * a[1] + ALPHA_C * t0.y;
  float o2 = wn * a[2] + ALPHA_C * t0.z, o3 = wn * a[3] + ALPHA_C * t0.w;
  float o4 = wn * a[4] + ALPHA_C * t1.x, o5 = wn * a[5] + ALPHA_C * t1.y;
  float o6 = wn * a[6] + ALPHA_C * t1.z, o7 = wn * a[7] + ALPHA_C * t1.w;
  uint4 p;
  p.x = pack_bf16(o0, o1);
  p.y = pack_bf16(o2, o3);
  p.z = pack_bf16(o4, o5);
  p.w = pack_bf16(o6, o7);
  *((uint4*)(Zn + (size_t)n * WH) + c) = p;
}

// ---------- epilogue: denorm + row-L2 (bf16 Z in) ----------
__global__ __launch_bounds__(256) void k_final(const ushortT* __restrict__ Zb,
                                               const int* __restrict__ nt,
                                               const float* __restrict__ mean,
                                               const float* __restrict__ stdv,
                                               float* __restrict__ out, int N) {
  int wv = threadIdx.x >> 6, lane = threadIdx.x & 63;
  int n = blockIdx.x * 4 + wv;
  if (n >= N) return;
  int t = nt[n];
  float zv = __uint_as_float((unsigned)Zb[(size_t)n * WH + lane] << 16);
  float z = zv * stdv[t * WH + lane] + mean[t * WH + lane];
  float s = z * z;
#pragma unroll
  for (int off = 32; off > 0; off >>= 1) s += __shfl_xor(s, off, 64);
  float r = 1.0f / fmaxf(sqrtf(s), 1e-12f);
  out[(size_t)n * WH + lane] = z * r;
}

extern "C" void kernel_launch(void* const* d_in, const int* in_sizes, int n_in,
                              void* d_out, int out_size, void* d_ws, size_t ws_size,
                              hipStream_t stream) {
  const float* X = (const float*)d_in[0];
  const float* W = (const float*)d_in[1];
  const float* bias = (const float*)d_in[2];
  const float* g = (const float*)d_in[3];
  const int* ei = (const int*)d_in[4];
  const int* nt = (const int*)d_in[5];

  const int N = in_sizes[5];
  const int E = in_sizes[4] / 2;
  const int M = in_sizes[3];  // N * WH
  const int NW = N * WH;
  const int* srcp = ei;
  const int* dstp = ei + E;

  char* w = (char*)d_ws;
  size_t o = 0;
  auto alloc = [&](size_t bytes) {
    size_t r = o;
    o += (bytes + 255) & ~(size_t)255;
    return r;
  };
  size_t off_stats = alloc(4096);  // counts@0, mean@256, std@1280
  size_t off_psum  = alloc((size_t)STATS_GRID * 256 * 4);
  size_t off_psq   = alloc((size_t)STATS_GRID * 256 * 4);
  size_t off_pcnt  = alloc((size_t)STATS_GRID * TT * 4);
  size_t off_diff  = alloc((size_t)BINS * 4);
  size_t off_bsum  = alloc((size_t)SB * 4);
  size_t off_degi  = alloc((size_t)N * 4);  // memset region start
  size_t off_cur   = alloc((size_t)N * 4);  // memset region end (256B-aligned slot!)
  size_t off_off   = alloc((size_t)N * 4);
  size_t off_esrc  = alloc((size_t)E * 4);
  size_t off_tilde = alloc((size_t)NW * 4);
  size_t off_tbf   = alloc((size_t)NW * 2);  // bf16 tilde (hop-0 gather source)
  size_t off_bufA  = alloc((size_t)NW * 4);  // partial hists alias; later bf16 Z ping
  size_t off_bufB  = alloc((size_t)NW * 4);  // partial hists alias; later bf16 Z pong

  float* counts = (float*)(w + off_stats + 0);
  float* mean   = (float*)(w + off_stats + 256);
  float* stdv   = (float*)(w + off_stats + 1280);
  float* psum   = (float*)(w + off_psum);
  float* psq    = (float*)(w + off_psq);
  float* pcnt   = (float*)(w + off_pcnt);
  int* diff     = (int*)(w + off_diff);
  unsigned* bsum = (unsigned*)(w + off_bsum);
  unsigned* degi = (unsigned*)(w + off_degi);
  unsigned* cur  = (unsigned*)(w + off_cur);
  unsigned* offp = (unsigned*)(w + off_off);
  unsigned* esrc = (unsigned*)(w + off_esrc);
  float* tilde   = (float*)(w + off_tilde);
  ushortT* tbf   = (ushortT*)(w + off_tbf);
  unsigned* pg   = (unsigned*)(w + off_bufA);
  unsigned* pe   = (unsigned*)(w + off_bufB);
  ushortT* ZA    = (ushortT*)(w + off_bufA);
  ushortT* ZB    = (ushortT*)(w + off_bufB);
  float* out = (float*)d_out;

  // zero degree+cursor; span covers the alignment pad between slots.
  hipMemsetAsync(w + off_degi, 0, off_cur - off_degi + (size_t)N * 4, stream);

  // 1) encode + L2 norm -> tilde buffer (holds H for now)
  k_encode<<<(N + ENC_BN - 1) / ENC_BN, ENC_T, 0, stream>>>(X, W, bias, tilde, N);

  // 2) per-type stats (fused sum/sumsq/count) + reduce
  k_stats<<<STATS_GRID, 256, 0, stream>>>(tilde, nt, psum, psq, pcnt, NW);
  k_reduce_stats<<<1, 256, 0, stream>>>(psum, psq, pcnt, mean, stdv, counts);

  // 3) tilde in place (+bf16 copy) + LDS histograms
  k_tilde_hist<<<HG, 256, 0, stream>>>(tilde, nt, mean, stdv, tbf, pe, NW);
  k_histG<<<HG, 256, 0, stream>>>(g, pg, M);

  // 4) W1 = (delta/M) * sum_b |prefix(cg-ce)|
  k_diff<<<BINS / 256, 256, 0, stream>>>(pg, pe, diff);
  k_wass<<<1, 1024, 0, stream>>>(diff, out, M, NW);

  // 5) CSR build — multi-block 3-phase scan + single-pass scatter
  k_degi<<<(E + 255) / 256, 256, 0, stream>>>(dstp, degi, E);
  k_scan_part<<<SB, ST, 0, stream>>>(degi, bsum, N);
  k_scan_mid<<<1, ST, 0, stream>>>(bsum);
  k_scan_apply<<<SB, ST, 0, stream>>>(degi, bsum, offp, N);
  k_build<<<(E + 255) / 256, 256, 0, stream>>>(srcp, dstp, offp, cur, esrc, E);

  // 6) K=10 diffusion hops, bf16 ping-pong (partial hists dead now)
  const ushortT* Zc = tbf;
  for (int k = 0; k < 10; ++k) {
    ushortT* Zn = (k & 1) ? ZB : ZA;
    k_spmm<<<(N + 31) / 32, 256, 0, stream>>>(offp, degi, esrc, Zc, tilde, Zn, N);
    Zc = Zn;
  }

  // 7) denorm + row L2 -> out
  k_final<<<(N + 3) / 4, 256, 0, stream>>>(Zc, nt, mean, stdv, out, N);
}

// Round 7
// 898.674 us; speedup vs baseline: 1.2180x; 1.1258x over previous
//
#include <hip/hip_runtime.h>
#include <math.h>

#define WH 64
#define WIN 256
#define TT 4
#define ALPHA_C 0.1f
#define STATS_GRID 256
#define KC 32
#define ENC_T 64
#define ENC_BN 32
#define XTS 36                  // 32 + 4: conflict-free a-reads, keeps 16B row align
#define BINS 16384              // bins over [-8, 8)
#define BIN_SCALE 1024.0f       // BINS / 16
#define HG 256                  // histogram grid (partial hists)
#define SB 128                  // scan blocks
#define ST 256                  // scan threads/block

typedef unsigned short ushortT;

__device__ __forceinline__ unsigned pack_bf16(float a, float b) {
  unsigned ua = __float_as_uint(a), ub = __float_as_uint(b);
  ua = (ua + 0x7FFFu + ((ua >> 16) & 1u)) >> 16;          // RNE
  ub = ((ub + 0x7FFFu + ((ub >> 16) & 1u)) >> 16) << 16;
  return (ua & 0xFFFFu) | ub;
}
__device__ __forceinline__ float bf_lo(unsigned p) { return __uint_as_float(p << 16); }
__device__ __forceinline__ float bf_hi(unsigned p) { return __uint_as_float(p & 0xFFFF0000u); }

// ---------- encode: H = l2norm_rows(X @ W + b) ----------
// 1-wave blocks (no inter-wave barriers), 32 nodes/block, 4x8 acc/thread.
__global__ __launch_bounds__(64, 3) void k_encode(const float* __restrict__ X,
                                                  const float* __restrict__ W,
                                                  const float* __restrict__ bias,
                                                  float* __restrict__ H, int N) {
  __shared__ __align__(16) float XsT[KC * XTS];  // 4.6 KB
  __shared__ __align__(16) float Ws[KC * WH];    // 8 KB
  int tid = threadIdx.x;
  int ng = tid >> 3, cg = tid & 7;   // ng: 8 node-groups of 4; cg: 8 col-groups of 8
  int nodeBase = blockIdx.x * ENC_BN;
  float acc[4][8] = {};
  for (int k0 = 0; k0 < WIN; k0 += KC) {
    __syncthreads();
    // stage W chunk: KC*WH = 2048 floats = 512 float4, 8 per thread
    const float4* Wg4 = (const float4*)(W + (size_t)k0 * WH);
    float4* Ws4 = (float4*)Ws;
#pragma unroll
    for (int j = 0; j < 8; ++j) Ws4[tid + j * 64] = Wg4[tid + j * 64];
    // stage X chunk transposed: 32 nodes x 32 k = 256 float4, 4 per thread
#pragma unroll
    for (int i = 0; i < 4; ++i) {
      int idx = tid + i * 64;
      int ln = idx >> 3, f4 = idx & 7;
      int node = nodeBase + ln;
      float4 xv = (node < N)
                      ? *(const float4*)(X + (size_t)node * WIN + k0 + f4 * 4)
                      : make_float4(0.f, 0.f, 0.f, 0.f);
      float* p = &XsT[(f4 * 4) * XTS + ln];
      p[0] = xv.x;
      p[XTS] = xv.y;
      p[2 * XTS] = xv.z;
      p[3 * XTS] = xv.w;
    }
    __syncthreads();
#pragma unroll 8
    for (int k = 0; k < KC; ++k) {
      float4 a0 = *(const float4*)&XsT[k * XTS + ng * 4];
      float4 b0 = *(const float4*)&Ws[k * WH + cg * 8];
      float4 b1 = *(const float4*)&Ws[k * WH + cg * 8 + 4];
      float av[4] = {a0.x, a0.y, a0.z, a0.w};
      float bb[8] = {b0.x, b0.y, b0.z, b0.w, b1.x, b1.y, b1.z, b1.w};
#pragma unroll
      for (int i = 0; i < 4; ++i)
#pragma unroll
        for (int j = 0; j < 8; ++j) acc[i][j] += av[i] * bb[j];
    }
  }
  float4 bb0 = *(const float4*)(bias + cg * 8);
  float4 bb1 = *(const float4*)(bias + cg * 8 + 4);
  float bv[8] = {bb0.x, bb0.y, bb0.z, bb0.w, bb1.x, bb1.y, bb1.z, bb1.w};
#pragma unroll
  for (int i = 0; i < 4; ++i) {
    float h[8];
    float s = 0.f;
#pragma unroll
    for (int j = 0; j < 8; ++j) {
      h[j] = acc[i][j] + bv[j];
      s += h[j] * h[j];
    }
    s += __shfl_xor(s, 1, 64);
    s += __shfl_xor(s, 2, 64);
    s += __shfl_xor(s, 4, 64);
    float r = 1.0f / fmaxf(sqrtf(s), 1e-12f);
    int node = nodeBase + ng * 4 + i;
    if (node < N) {
      float4 o0 = {h[0] * r, h[1] * r, h[2] * r, h[3] * r};
      float4 o1 = {h[4] * r, h[5] * r, h[6] * r, h[7] * r};
      *(float4*)(H + (size_t)node * WH + cg * 8) = o0;
      *(float4*)(H + (size_t)node * WH + cg * 8 + 4) = o1;
    }
  }
}

// ---------- per-type stats: fused sum + sumsq + counts ----------
__global__ __launch_bounds__(256) void k_stats(const float* __restrict__ H,
                                               const int* __restrict__ nt,
                                               float* __restrict__ psum,
                                               float* __restrict__ psq,
                                               float* __restrict__ pcnt, int NW) {
  __shared__ float ls[TT * WH], ls2[TT * WH];
  __shared__ float lc[TT];
  ls[threadIdx.x] = 0.0f;
  ls2[threadIdx.x] = 0.0f;
  if (threadIdx.x < TT) lc[threadIdx.x] = 0.0f;
  __syncthreads();
  for (int i = blockIdx.x * 256 + threadIdx.x; i < NW; i += STATS_GRID * 256) {
    int nn = i >> 6, d = i & 63;
    int t = nt[nn];
    float v = H[i];
    atomicAdd(&ls[t * WH + d], v);
    atomicAdd(&ls2[t * WH + d], v * v);
    if (d == 0) atomicAdd(&lc[t], 1.0f);
  }
  __syncthreads();
  psum[blockIdx.x * 256 + threadIdx.x] = ls[threadIdx.x];
  psq[blockIdx.x * 256 + threadIdx.x] = ls2[threadIdx.x];
  if (threadIdx.x < TT) pcnt[blockIdx.x * TT + threadIdx.x] = lc[threadIdx.x];
}

__global__ __launch_bounds__(256) void k_reduce_stats(const float* __restrict__ psum,
                                                      const float* __restrict__ psq,
                                                      const float* __restrict__ pcnt,
                                                      float* __restrict__ mean,
                                                      float* __restrict__ stdv,
                                                      float* __restrict__ counts) {
  __shared__ float c[TT];
  if (threadIdx.x < TT) {
    float s = 0.0f;
    for (int b = 0; b < STATS_GRID; ++b) s += pcnt[b * TT + threadIdx.x];
    counts[threadIdx.x] = s;
    c[threadIdx.x] = s;
  }
  __syncthreads();
  float s = 0.0f, q = 0.0f;
  for (int b = 0; b < STATS_GRID; ++b) {
    s += psum[b * 256 + threadIdx.x];
    q += psq[b * 256 + threadIdx.x];
  }
  float n = c[threadIdx.x >> 6];
  float m = s / n;
  mean[threadIdx.x] = m;
  stdv[threadIdx.x] = (q - s * s / n) / sqrtf(n - 1.0f);
}

// tilde = (H - mean)/std in place + bf16 copy; LDS-private histogram -> partial dump
__global__ __launch_bounds__(256) void k_tilde_hist(float* __restrict__ H,
                                                    const int* __restrict__ nt,
                                                    const float* __restrict__ mean,
                                                    const float* __restrict__ stdv,
                                                    ushortT* __restrict__ tb,
                                                    unsigned* __restrict__ pe, int NW) {
  __shared__ unsigned hist[BINS];
  for (int b = threadIdx.x; b < BINS; b += 256) hist[b] = 0;
  __syncthreads();
  for (int i = blockIdx.x * 256 + threadIdx.x; i < NW; i += HG * 256) {
    int nn = i >> 6, d = i & 63;
    int t = nt[nn];
    float v = (H[i] - mean[t * WH + d]) / stdv[t * WH + d];
    H[i] = v;
    unsigned u = __float_as_uint(v);
    tb[i] = (ushortT)((u + 0x7FFFu + ((u >> 16) & 1u)) >> 16);
    int b = (int)((v + 8.0f) * BIN_SCALE);
    b = min(max(b, 0), BINS - 1);
    atomicAdd(&hist[b], 1u);
  }
  __syncthreads();
  for (int b = threadIdx.x; b < BINS; b += 256)
    pe[(size_t)blockIdx.x * BINS + b] = hist[b];
}

__global__ __launch_bounds__(256) void k_histG(const float* __restrict__ g,
                                               unsigned* __restrict__ pg, int M) {
  __shared__ unsigned hist[BINS];
  for (int b = threadIdx.x; b < BINS; b += 256) hist[b] = 0;
  __syncthreads();
  for (int i = blockIdx.x * 256 + threadIdx.x; i < M; i += HG * 256) {
    float v = g[i];
    int b = (int)((v + 8.0f) * BIN_SCALE);
    b = min(max(b, 0), BINS - 1);
    atomicAdd(&hist[b], 1u);
  }
  __syncthreads();
  for (int b = threadIdx.x; b < BINS; b += 256)
    pg[(size_t)blockIdx.x * BINS + b] = hist[b];
}

__global__ __launch_bounds__(256) void k_diff(const unsigned* __restrict__ pg,
                                              const unsigned* __restrict__ pe,
                                              int* __restrict__ diff) {
  int b = blockIdx.x * 256 + threadIdx.x;
  int s = 0;
  for (int p = 0; p < HG; ++p)
    s += (int)pg[(size_t)p * BINS + b] - (int)pe[(size_t)p * BINS + b];
  diff[b] = s;
}

__global__ __launch_bounds__(1024) void k_wass(const int* __restrict__ diff,
                                               float* __restrict__ out, int M, int NW) {
  int tid = threadIdx.x;
  int lo = tid * (BINS / 1024);
  int d[BINS / 1024];
  int s = 0;
#pragma unroll
  for (int i = 0; i < BINS / 1024; ++i) {
    d[i] = diff[lo + i];
    s += d[i];
  }
  __shared__ int sc[1024];
  sc[tid] = s;
  __syncthreads();
  for (int st = 1; st < 1024; st <<= 1) {
    int v = (tid >= st) ? sc[tid - st] : 0;
    __syncthreads();
    sc[tid] += v;
    __syncthreads();
  }
  int run = sc[tid] - s;
  long long a = 0;
#pragma unroll
  for (int i = 0; i < BINS / 1024; ++i) {
    run += d[i];
    a += (long long)(run < 0 ? -run : run);
  }
  __shared__ long long rd[1024];
  rd[tid] = a;
  __syncthreads();
  for (int st = 512; st > 0; st >>= 1) {
    if (tid < st) rd[tid] += rd[tid + st];
    __syncthreads();
  }
  if (tid == 0) out[NW] = (float)((double)rd[0] * (1.0 / (double)BIN_SCALE) / (double)M);
}

// ---------- CSR build ----------
__global__ __launch_bounds__(256) void k_degi(const int* __restrict__ dst,
                                              unsigned* __restrict__ degi, int E) {
  int e = blockIdx.x * 256 + threadIdx.x;
  if (e < E) atomicAdd(&degi[dst[e]], 1u);
}

// ---------- device-wide exclusive scan, 3 phases over SB blocks ----------
__global__ __launch_bounds__(ST) void k_scan_part(const unsigned* __restrict__ in,
                                                  unsigned* __restrict__ bsum, int L) {
  int C = (L + SB * ST - 1) / (SB * ST);
  int base = (blockIdx.x * ST + threadIdx.x) * C;
  int hi = min(base + C, L);
  unsigned s = 0;
  for (int i = base; i < hi; ++i) s += in[i];
  __shared__ unsigned red[ST];
  red[threadIdx.x] = s;
  __syncthreads();
  for (int st = ST / 2; st > 0; st >>= 1) {
    if (threadIdx.x < st) red[threadIdx.x] += red[threadIdx.x + st];
    __syncthreads();
  }
  if (threadIdx.x == 0) bsum[blockIdx.x] = red[0];
}
__global__ __launch_bounds__(ST) void k_scan_mid(unsigned* __restrict__ bsum) {
  __shared__ unsigned ts[ST];
  unsigned v = (threadIdx.x < SB) ? bsum[threadIdx.x] : 0u;
  ts[threadIdx.x] = v;
  __syncthreads();
  for (int st = 1; st < ST; st <<= 1) {
    unsigned u = (threadIdx.x >= (unsigned)st) ? ts[threadIdx.x - st] : 0u;
    __syncthreads();
    ts[threadIdx.x] += u;
    __syncthreads();
  }
  if (threadIdx.x < SB) bsum[threadIdx.x] = ts[threadIdx.x] - v;
}
__global__ __launch_bounds__(ST) void k_scan_apply(const unsigned* __restrict__ in,
                                                   const unsigned* __restrict__ bsum,
                                                   unsigned* __restrict__ outp, int L) {
  int C = (L + SB * ST - 1) / (SB * ST);
  int base = (blockIdx.x * ST + threadIdx.x) * C;
  int hi = min(base + C, L);
  unsigned s = 0;
  for (int i = base; i < hi; ++i) s += in[i];
  __shared__ unsigned ts[ST];
  ts[threadIdx.x] = s;
  __syncthreads();
  for (int st = 1; st < ST; st <<= 1) {
    unsigned u = (threadIdx.x >= (unsigned)st) ? ts[threadIdx.x - st] : 0u;
    __syncthreads();
    ts[threadIdx.x] += u;
    __syncthreads();
  }
  unsigned run = bsum[blockIdx.x] + ts[threadIdx.x] - s;
  for (int i = base; i < hi; ++i) {
    unsigned c = in[i];
    outp[i] = run;
    run += c;
  }
}

// single-pass scatter (measured faster than dst-partitioned 4-pass: latency-
// bound, not write-BW-bound -- R4 post-mortem)
__global__ __launch_bounds__(256) void k_build(const int* __restrict__ src,
                                               const int* __restrict__ dst,
                                               const unsigned* __restrict__ off,
                                               unsigned* __restrict__ cur,
                                               unsigned* __restrict__ esrc, int E) {
  int e = blockIdx.x * 256 + threadIdx.x;
  if (e >= E) return;
  int t = dst[e];
  unsigned p = off[t] + atomicAdd(&cur[t], 1u);
  esrc[p] = (unsigned)src[e];
}

// ---------- diffusion hop (bf16 Z) ----------
// 8 lanes per node, 8 nodes per wave. Edge loop unrolled x4: 4 index loads
// issued together, then 4 gathers in flight -> ~4x MLP vs serial chain
// (R6 post-mortem: hop was latency-bound at ~1 edge in flight per lane).
// fin!=0: fuse denorm + row-L2 epilogue, write fp32 to outp (skips Zn).
__global__ __launch_bounds__(256) void k_spmm(const unsigned* __restrict__ off,
                                              const unsigned* __restrict__ degi,
                                              const unsigned* __restrict__ esrc,
                                              const ushortT* __restrict__ Zb,
                                              const float* __restrict__ tilde,
                                              ushortT* __restrict__ Zn,
                                              const int* __restrict__ nt,
                                              const float* __restrict__ mean,
                                              const float* __restrict__ stdv,
                                              float* __restrict__ outp,
                                              int fin, int N) {
  int lane = threadIdx.x & 63, wv = threadIdx.x >> 6;
  int j = lane >> 3, c = lane & 7;   // j: node slot, c: col-eighth
  int n = blockIdx.x * 32 + wv * 8 + j;
  if (n >= N) return;
  unsigned st = off[n], dg = degi[n];
  const unsigned* ep = esrc + st;
  float a[8] = {};
  unsigned e = 0;
  for (; e + 4 <= dg; e += 4) {
    unsigned s0 = ep[e], s1 = ep[e + 1], s2 = ep[e + 2], s3 = ep[e + 3];
    uint4 v0 = *((const uint4*)(Zb + (size_t)s0 * WH) + c);
    uint4 v1 = *((const uint4*)(Zb + (size_t)s1 * WH) + c);
    uint4 v2 = *((const uint4*)(Zb + (size_t)s2 * WH) + c);
    uint4 v3 = *((const uint4*)(Zb + (size_t)s3 * WH) + c);
    a[0] += bf_lo(v0.x) + bf_lo(v1.x) + bf_lo(v2.x) + bf_lo(v3.x);
    a[1] += bf_hi(v0.x) + bf_hi(v1.x) + bf_hi(v2.x) + bf_hi(v3.x);
    a[2] += bf_lo(v0.y) + bf_lo(v1.y) + bf_lo(v2.y) + bf_lo(v3.y);
    a[3] += bf_hi(v0.y) + bf_hi(v1.y) + bf_hi(v2.y) + bf_hi(v3.y);
    a[4] += bf_lo(v0.z) + bf_lo(v1.z) + bf_lo(v2.z) + bf_lo(v3.z);
    a[5] += bf_hi(v0.z) + bf_hi(v1.z) + bf_hi(v2.z) + bf_hi(v3.z);
    a[6] += bf_lo(v0.w) + bf_lo(v1.w) + bf_lo(v2.w) + bf_lo(v3.w);
    a[7] += bf_hi(v0.w) + bf_hi(v1.w) + bf_hi(v2.w) + bf_hi(v3.w);
  }
  for (; e < dg; ++e) {
    unsigned s = ep[e];
    uint4 v = *((const uint4*)(Zb + (size_t)s * WH) + c);
    a[0] += bf_lo(v.x); a[1] += bf_hi(v.x);
    a[2] += bf_lo(v.y); a[3] += bf_hi(v.y);
    a[4] += bf_lo(v.z); a[5] += bf_hi(v.z);
    a[6] += bf_lo(v.w); a[7] += bf_hi(v.w);
  }
  float wn = (1.0f - ALPHA_C) / fmaxf((float)dg, 1.0f);
  const float4* Tr = (const float4*)(tilde + (size_t)n * WH);
  float4 t0 = Tr[2 * c], t1 = Tr[2 * c + 1];
  float o0 = wn * a[0] + ALPHA_C * t0.x, o1 = wn * a[1] + ALPHA_C * t0.y;
  float o2 = wn * a[2] + ALPHA_C * t0.z, o3 = wn * a[3] + ALPHA_C * t0.w;
  float o4 = wn * a[4] + ALPHA_C * t1.x, o5 = wn * a[5] + ALPHA_C * t1.y;
  float o6 = wn * a[6] + ALPHA_C * t1.z, o7 = wn * a[7] + ALPHA_C * t1.w;
  if (!fin) {
    uint4 p;
    p.x = pack_bf16(o0, o1);
    p.y = pack_bf16(o2, o3);
    p.z = pack_bf16(o4, o5);
    p.w = pack_bf16(o6, o7);
    *((uint4*)(Zn + (size_t)n * WH) + c) = p;
  } else {
    int t = nt[n];
    float4 m0 = *(const float4*)(mean + t * WH + c * 8);
    float4 m1 = *(const float4*)(mean + t * WH + c * 8 + 4);
    float4 d0 = *(const float4*)(stdv + t * WH + c * 8);
    float4 d1 = *(const float4*)(stdv + t * WH + c * 8 + 4);
    float z0 = o0 * d0.x + m0.x, z1 = o1 * d0.y + m0.y;
    float z2 = o2 * d0.z + m0.z, z3 = o3 * d0.w + m0.w;
    float z4 = o4 * d1.x + m1.x, z5 = o5 * d1.y + m1.y;
    float z6 = o6 * d1.z + m1.z, z7 = o7 * d1.w + m1.w;
    float s = z0 * z0 + z1 * z1 + z2 * z2 + z3 * z3 +
              z4 * z4 + z5 * z5 + z6 * z6 + z7 * z7;
    s += __shfl_xor(s, 1, 64);
    s += __shfl_xor(s, 2, 64);
    s += __shfl_xor(s, 4, 64);
    float r = 1.0f / fmaxf(sqrtf(s), 1e-12f);
    float4 w0 = {z0 * r, z1 * r, z2 * r, z3 * r};
    float4 w1 = {z4 * r, z5 * r, z6 * r, z7 * r};
    *(float4*)(outp + (size_t)n * WH + c * 8) = w0;
    *(float4*)(outp + (size_t)n * WH + c * 8 + 4) = w1;
  }
}

extern "C" void kernel_launch(void* const* d_in, const int* in_sizes, int n_in,
                              void* d_out, int out_size, void* d_ws, size_t ws_size,
                              hipStream_t stream) {
  const float* X = (const float*)d_in[0];
  const float* W = (const float*)d_in[1];
  const float* bias = (const float*)d_in[2];
  const float* g = (const float*)d_in[3];
  const int* ei = (const int*)d_in[4];
  const int* nt = (const int*)d_in[5];

  const int N = in_sizes[5];
  const int E = in_sizes[4] / 2;
  const int M = in_sizes[3];  // N * WH
  const int NW = N * WH;
  const int* srcp = ei;
  const int* dstp = ei + E;

  char* w = (char*)d_ws;
  size_t o = 0;
  auto alloc = [&](size_t bytes) {
    size_t r = o;
    o += (bytes + 255) & ~(size_t)255;
    return r;
  };
  size_t off_stats = alloc(4096);  // counts@0, mean@256, std@1280
  size_t off_psum  = alloc((size_t)STATS_GRID * 256 * 4);
  size_t off_psq   = alloc((size_t)STATS_GRID * 256 * 4);
  size_t off_pcnt  = alloc((size_t)STATS_GRID * TT * 4);
  size_t off_diff  = alloc((size_t)BINS * 4);
  size_t off_bsum  = alloc((size_t)SB * 4);
  size_t off_degi  = alloc((size_t)N * 4);  // memset region start
  size_t off_cur   = alloc((size_t)N * 4);  // memset region end (256B-aligned slot!)
  size_t off_off   = alloc((size_t)N * 4);
  size_t off_esrc  = alloc((size_t)E * 4);
  size_t off_tilde = alloc((size_t)NW * 4);
  size_t off_tbf   = alloc((size_t)NW * 2);  // bf16 tilde (hop-0 gather source)
  size_t off_bufA  = alloc((size_t)NW * 4);  // partial hists alias; later bf16 Z ping
  size_t off_bufB  = alloc((size_t)NW * 4);  // partial hists alias; later bf16 Z pong

  float* counts = (float*)(w + off_stats + 0);
  float* mean   = (float*)(w + off_stats + 256);
  float* stdv   = (float*)(w + off_stats + 1280);
  float* psum   = (float*)(w + off_psum);
  float* psq    = (float*)(w + off_psq);
  float* pcnt   = (float*)(w + off_pcnt);
  int* diff     = (int*)(w + off_diff);
  unsigned* bsum = (unsigned*)(w + off_bsum);
  unsigned* degi = (unsigned*)(w + off_degi);
  unsigned* cur  = (unsigned*)(w + off_cur);
  unsigned* offp = (unsigned*)(w + off_off);
  unsigned* esrc = (unsigned*)(w + off_esrc);
  float* tilde   = (float*)(w + off_tilde);
  ushortT* tbf   = (ushortT*)(w + off_tbf);
  unsigned* pg   = (unsigned*)(w + off_bufA);
  unsigned* pe   = (unsigned*)(w + off_bufB);
  ushortT* ZA    = (ushortT*)(w + off_bufA);
  ushortT* ZB    = (ushortT*)(w + off_bufB);
  float* out = (float*)d_out;

  // zero degree+cursor; span covers the alignment pad between slots.
  hipMemsetAsync(w + off_degi, 0, off_cur - off_degi + (size_t)N * 4, stream);

  // 1) encode + L2 norm -> tilde buffer (holds H for now)
  k_encode<<<(N + ENC_BN - 1) / ENC_BN, ENC_T, 0, stream>>>(X, W, bias, tilde, N);

  // 2) per-type stats (fused sum/sumsq/count) + reduce
  k_stats<<<STATS_GRID, 256, 0, stream>>>(tilde, nt, psum, psq, pcnt, NW);
  k_reduce_stats<<<1, 256, 0, stream>>>(psum, psq, pcnt, mean, stdv, counts);

  // 3) tilde in place (+bf16 copy) + LDS histograms
  k_tilde_hist<<<HG, 256, 0, stream>>>(tilde, nt, mean, stdv, tbf, pe, NW);
  k_histG<<<HG, 256, 0, stream>>>(g, pg, M);

  // 4) W1 = (delta/M) * sum_b |prefix(cg-ce)|
  k_diff<<<BINS / 256, 256, 0, stream>>>(pg, pe, diff);
  k_wass<<<1, 1024, 0, stream>>>(diff, out, M, NW);

  // 5) CSR build — multi-block 3-phase scan + single-pass scatter
  k_degi<<<(E + 255) / 256, 256, 0, stream>>>(dstp, degi, E);
  k_scan_part<<<SB, ST, 0, stream>>>(degi, bsum, N);
  k_scan_mid<<<1, ST, 0, stream>>>(bsum);
  k_scan_apply<<<SB, ST, 0, stream>>>(degi, bsum, offp, N);
  k_build<<<(E + 255) / 256, 256, 0, stream>>>(srcp, dstp, offp, cur, esrc, E);

  // 6) K=10 diffusion hops, bf16 ping-pong; hop 10 fuses denorm+L2 -> out
  const ushortT* Zc = tbf;
  for (int k = 0; k < 10; ++k) {
    ushortT* Zn = (k & 1) ? ZB : ZA;
    int fin = (k == 9) ? 1 : 0;
    k_spmm<<<(N + 31) / 32, 256, 0, stream>>>(offp, degi, esrc, Zc, tilde, Zn,
                                              nt, mean, stdv, out, fin, N);
    Zc = Zn;
  }
}